// Round 4
// baseline (283.794 us; speedup 1.0000x reference)
//
#include <hip/hip_runtime.h>
#include <math.h>
#include <stdint.h>

// Single-head GAT layer, MI355X (gfx950).
//   k_zero    : zero per-dst degree counters
//   k_hist    : deg[dst[e]]++  (atomics on 200KB L2-resident array)
//   k_scan    : exclusive prefix sum of deg -> off (single 1024-thr block)
//   k_scatter : adj[atomicAdd(&off[d],1)] = (u16)src[e]  (compact 1.6MB CSR)
//   k_wconv   : W f32[256][64] -> f16 B-fragment-ordered Wf (32KB, L2-resident)
//   k_gemmf16 : z = X@W via mfma_f32_16x16x32_f16, fused el/er; z stored f16
//   k_agg     : per-dst wave: online segment softmax + weighted gather of z

constexpr int IN_D   = 256;
constexpr int OUT_D  = 64;
constexpr int WAVES_PB = 4;

typedef _Float16 f16x8 __attribute__((ext_vector_type(8)));
typedef float    f32x4 __attribute__((ext_vector_type(4)));

__device__ __forceinline__ void gload_lds16(const void* g, void* l) {
    __builtin_amdgcn_global_load_lds(
        (const __attribute__((address_space(1))) uint32_t*)g,
        (__attribute__((address_space(3))) uint32_t*)l, 16, 0, 0);
}

__global__ void k_zero(int* __restrict__ deg, int n) {
    int i = blockIdx.x * 256 + threadIdx.x;
    if (i < n) deg[i] = 0;
}

__global__ void k_hist(const int* __restrict__ dst, int* __restrict__ deg, int E) {
    int e = blockIdx.x * 256 + threadIdx.x;
    if (e < E) atomicAdd(&deg[dst[e]], 1);
}

// Exclusive scan of deg[0..n) -> off[0..n). One block, 1024 threads.
__global__ __launch_bounds__(1024) void k_scan(const int* __restrict__ deg,
                                               int* __restrict__ off, int n) {
    __shared__ int part[1024];
    const int t = threadIdx.x;
    const int chunk = (n + 1023) >> 10;
    const int lo = t * chunk;
    const int hi = (lo + chunk < n) ? lo + chunk : n;
    int s = 0;
    for (int i = lo; i < hi; ++i) s += deg[i];
    part[t] = s;
    __syncthreads();
    int v = s;
    for (int ofs = 1; ofs < 1024; ofs <<= 1) {
        int u = (t >= ofs) ? part[t - ofs] : 0;
        __syncthreads();
        v += u;
        part[t] = v;
        __syncthreads();
    }
    int run = v - s;                       // exclusive prefix of this chunk
    for (int i = lo; i < hi; ++i) { off[i] = run; run += deg[i]; }
}

// Scatter src ids into CSR. atomicAdd on off[] itself serves as the cursor;
// after this kernel off[d] == segment END (base = off[d] - deg[d]).
__global__ void k_scatter(const int* __restrict__ dst, const int* __restrict__ src,
                          int* __restrict__ off, uint16_t* __restrict__ adj, int E) {
    int e = blockIdx.x * 256 + threadIdx.x;
    if (e < E) {
        int d = dst[e];
        int pos = atomicAdd(&off[d], 1);
        adj[pos] = (uint16_t)src[e];
    }
}

// Wf[t] for t = ((kc*4+ct)*64 + lane)*8 + j  holds W[kc*32+(lane>>4)*8+j][ct*16+(lane&15)]
__global__ void k_wconv(const float* __restrict__ W, _Float16* __restrict__ Wf) {
    int t = blockIdx.x * 256 + threadIdx.x;          // 16384 total
    int j    = t & 7;
    int lane = (t >> 3) & 63;
    int ct   = (t >> 9) & 3;
    int kc   = t >> 11;
    int k = kc * 32 + (lane >> 4) * 8 + j;
    int c = ct * 16 + (lane & 15);
    Wf[t] = (_Float16)W[k * OUT_D + c];
}

// Block: 256 thr / 4 waves; wave: 16 rows x 64 cols, K=256 in 8 chunks.
// C/D layout (m89): col = lane&15, row = (lane>>4)*4 + reg.
__global__ __launch_bounds__(256) void k_gemmf16(
        const float* __restrict__ feat, const _Float16* __restrict__ Wf,
        const float* __restrict__ a,
        _Float16* __restrict__ z, float* __restrict__ el, float* __restrict__ er,
        int n)
{
    __shared__ __align__(16) _Float16 WfL[IN_D * OUT_D];   // 32 KB, frag order

    const int tid  = threadIdx.x;
    const int lane = tid & 63;
    const int wv   = tid >> 6;
    const int row0 = blockIdx.x * 64 + wv * 16;
    const int kg   = lane >> 4;

    int gr = row0 + (lane & 15); if (gr > n - 1) gr = n - 1;
    const float* frow = feat + (size_t)gr * IN_D;
    float4 r0[8], r1[8];
    #pragma unroll
    for (int kc = 0; kc < 8; ++kc) {
        const float4* fp = (const float4*)(frow + kc * 32 + kg * 8);
        r0[kc] = fp[0];
        r1[kc] = fp[1];
    }

    #pragma unroll
    for (int i = 0; i < 8; ++i) {
        const char* gsrc = (const char*)Wf + (size_t)(i * 256 + tid) * 16;
        char* ldst = (char*)WfL + (size_t)(i * 256 + wv * 64) * 16;
        gload_lds16(gsrc, ldst);
    }
    __syncthreads();

    f32x4 acc[4];
    #pragma unroll
    for (int ct = 0; ct < 4; ++ct) acc[ct] = (f32x4){0.f, 0.f, 0.f, 0.f};

    #pragma unroll
    for (int kc = 0; kc < 8; ++kc) {
        f16x8 af;
        af[0] = (_Float16)r0[kc].x; af[1] = (_Float16)r0[kc].y;
        af[2] = (_Float16)r0[kc].z; af[3] = (_Float16)r0[kc].w;
        af[4] = (_Float16)r1[kc].x; af[5] = (_Float16)r1[kc].y;
        af[6] = (_Float16)r1[kc].z; af[7] = (_Float16)r1[kc].w;
        #pragma unroll
        for (int ct = 0; ct < 4; ++ct) {
            f16x8 bf = *(const f16x8*)&WfL[((kc * 4 + ct) * 64 + lane) * 8];
            acc[ct] = __builtin_amdgcn_mfma_f32_16x16x32_f16(af, bf, acc[ct], 0, 0, 0);
        }
    }

    const int col = lane & 15;
    float av[4], bv[4];
    #pragma unroll
    for (int ct = 0; ct < 4; ++ct) {
        av[ct] = a[ct * 16 + col];
        bv[ct] = a[OUT_D + ct * 16 + col];
    }
    #pragma unroll
    for (int i = 0; i < 4; ++i) {
        const int r = row0 + (lane >> 4) * 4 + i;
        float vl = 0.f, vr = 0.f;
        #pragma unroll
        for (int ct = 0; ct < 4; ++ct) {
            float zv = acc[ct][i];
            if (r < n) z[(size_t)r * OUT_D + ct * 16 + col] = (_Float16)zv;
            vl = fmaf(zv, av[ct], vl);
            vr = fmaf(zv, bv[ct], vr);
        }
        #pragma unroll
        for (int msk = 8; msk >= 1; msk >>= 1) {
            vl += __shfl_xor(vl, msk, 64);
            vr += __shfl_xor(vr, msk, 64);
        }
        if (col == 0 && r < n) { el[r] = vl; er[r] = vr; }
    }
}

// One wave per destination node; lane = output column. Single-pass online
// softmax (flash-style rescale); s/ex broadcast via shfl -- no LDS.
__global__ __launch_bounds__(256) void k_agg(
        const _Float16* __restrict__ z, const float* __restrict__ el,
        const float* __restrict__ er, const int* __restrict__ deg_,
        const int* __restrict__ off_, const uint16_t* __restrict__ adj,
        float* __restrict__ out, int n)
{
    const int lane = threadIdx.x & 63;
    const int wv   = threadIdx.x >> 6;
    const int d = blockIdx.x * WAVES_PB + wv;
    if (d >= n) return;

    const int deg  = deg_[d];
    const int base = off_[d] - deg;        // off[d] is segment END post-scatter
    const float erd = er[d];

    float m = -INFINITY, den = 0.f, acc = 0.f;
    for (int b0 = 0; b0 < deg; b0 += 64) {
        const int i = b0 + lane;
        int s = 0;
        float lgv = -INFINITY;
        if (i < deg) {
            s = adj[base + i];
            float x = el[s] + erd;
            lgv = x > 0.f ? x : 0.01f * x;   // leaky_relu(0.01)
        }
        float cm = lgv;
        #pragma unroll
        for (int msk = 32; msk >= 1; msk >>= 1) cm = fmaxf(cm, __shfl_xor(cm, msk, 64));
        const float newm = fmaxf(m, cm);
        const float ex = (i < deg) ? __expf(lgv - newm) : 0.f;
        float sum = ex;
        #pragma unroll
        for (int msk = 32; msk >= 1; msk >>= 1) sum += __shfl_xor(sum, msk, 64);
        const float scale = __expf(m - newm);   // first iter: exp(-inf)=0
        den = den * scale + sum;
        acc *= scale;
        m = newm;

        const int cd  = (deg - b0 < 64) ? deg - b0 : 64;
        const int cd8 = (cd + 7) & ~7;          // ex==0 for j>=cd, s==0 safe
        for (int j = 0; j < cd8; j += 8) {
            #pragma unroll
            for (int u = 0; u < 8; ++u) {
                const int   sj = __shfl(s, j + u, 64);
                const float wj = __shfl(ex, j + u, 64);
                acc = fmaf(wj, (float)z[(size_t)sj * OUT_D + lane], acc);
            }
        }
    }
    const float h = (deg > 0) ? acc / den : 0.f;
    out[(size_t)d * OUT_D + lane] = h > 0.f ? h : expm1f(h);  // elu
}

extern "C" void kernel_launch(void* const* d_in, const int* in_sizes, int n_in,
                              void* d_out, int out_size, void* d_ws, size_t ws_size,
                              hipStream_t stream) {
    const float* feat = (const float*)d_in[0];
    const float* W    = (const float*)d_in[1];
    const float* a    = (const float*)d_in[2];
    const int*   src  = (const int*)d_in[3];
    const int*   dst  = (const int*)d_in[4];
    const int n = in_sizes[0] / IN_D;
    const int E = in_sizes[3];
    float* out = (float*)d_out;

    // ws layout: z_h(f16) | el | er | deg | off | Wf(f16) | adj(u16)
    char* ws = (char*)d_ws;
    _Float16* z_h = (_Float16*)ws;  ws += (size_t)n * OUT_D * 2;
    float* el = (float*)ws;         ws += (size_t)n * 4;
    float* er = (float*)ws;         ws += (size_t)n * 4;
    int*  deg = (int*)ws;           ws += (size_t)n * 4;
    int*  off = (int*)ws;           ws += (size_t)n * 4;
    _Float16* Wf = (_Float16*)ws;   ws += (size_t)IN_D * OUT_D * 2;
    uint16_t* adj = (uint16_t*)ws;

    k_zero<<<(n + 255) / 256, 256, 0, stream>>>(deg, n);
    k_hist<<<(E + 255) / 256, 256, 0, stream>>>(dst, deg, E);
    k_scan<<<1, 1024, 0, stream>>>(deg, off, n);
    k_scatter<<<(E + 255) / 256, 256, 0, stream>>>(dst, src, off, adj, E);
    k_wconv<<<IN_D * OUT_D / 256, 256, 0, stream>>>(W, Wf);
    k_gemmf16<<<(n + 63) / 64, 256, 0, stream>>>(feat, Wf, a, z_h, el, er, n);
    k_agg<<<(n + WAVES_PB - 1) / WAVES_PB, 256, 0, stream>>>(z_h, el, er, deg, off, adj, out, n);
}

// Round 5
// 213.834 us; speedup vs baseline: 1.3272x; 1.3272x over previous
//
#include <hip/hip_runtime.h>
#include <math.h>
#include <stdint.h>

// Single-head GAT layer, MI355X (gfx950).
//   k_zero    : zero degree counters + allocator cursor
//   k_hist    : deg[dst[e]]++  (atomics, 200KB L2-resident)
//   k_alloc   : per-wave shfl-scan of deg + one atomicAdd per wave -> off[]
//               (segment bases in arbitrary order; off[d] = segment START)
//   k_scatter : adj[atomicAdd(&off[d],1)] = (u16)src[e]; off[d] ends at END
//   k_wconv   : W f32[256][64] -> f16 B-fragment-ordered Wf (32KB)
//   k_gemmf16 : z = X@W via mfma_f32_16x16x32_f16, fused el/er; z stored f16
//   k_agg     : per-dst wave: online segment softmax + weighted gather of z

constexpr int IN_D   = 256;
constexpr int OUT_D  = 64;
constexpr int WAVES_PB = 4;

typedef _Float16 f16x8 __attribute__((ext_vector_type(8)));
typedef float    f32x4 __attribute__((ext_vector_type(4)));

__device__ __forceinline__ void gload_lds16(const void* g, void* l) {
    __builtin_amdgcn_global_load_lds(
        (const __attribute__((address_space(1))) uint32_t*)g,
        (__attribute__((address_space(3))) uint32_t*)l, 16, 0, 0);
}

__global__ void k_zero(int* __restrict__ deg, int* __restrict__ counter, int n) {
    int i = blockIdx.x * 256 + threadIdx.x;
    if (i < n) deg[i] = 0;
    if (i == n) *counter = 0;
}

__global__ void k_hist(const int* __restrict__ dst, int* __restrict__ deg, int E) {
    int e = blockIdx.x * 256 + threadIdx.x;
    if (e < E) atomicAdd(&deg[dst[e]], 1);
}

// Allocate contiguous segment per node, order-free: wave-level inclusive scan
// of 64 degrees + one atomicAdd of the wave total on a global cursor.
__global__ void k_alloc(const int* __restrict__ deg, int* __restrict__ off,
                        int* __restrict__ counter, int n) {
    const int i = blockIdx.x * 256 + threadIdx.x;
    const int lane = threadIdx.x & 63;
    const int d = (i < n) ? deg[i] : 0;
    int inc = d;
    #pragma unroll
    for (int ofs = 1; ofs < 64; ofs <<= 1) {
        int u = __shfl_up(inc, ofs, 64);
        if (lane >= ofs) inc += u;
    }
    int base = 0;
    if (lane == 63) base = atomicAdd(counter, inc);   // inc@63 = wave total
    base = __shfl(base, 63, 64);
    if (i < n) off[i] = base + inc - d;               // exclusive start
}

// Scatter src ids. atomicAdd on off[] is the cursor; post-scatter off[d]=END.
__global__ void k_scatter(const int* __restrict__ dst, const int* __restrict__ src,
                          int* __restrict__ off, uint16_t* __restrict__ adj, int E) {
    int e = blockIdx.x * 256 + threadIdx.x;
    if (e < E) {
        int d = dst[e];
        int pos = atomicAdd(&off[d], 1);
        adj[pos] = (uint16_t)src[e];
    }
}

// Wf[t], t = ((kc*4+ct)*64+lane)*8+j  holds W[kc*32+(lane>>4)*8+j][ct*16+(lane&15)]
__global__ void k_wconv(const float* __restrict__ W, _Float16* __restrict__ Wf) {
    int t = blockIdx.x * 256 + threadIdx.x;          // 16384 total
    int j    = t & 7;
    int lane = (t >> 3) & 63;
    int ct   = (t >> 9) & 3;
    int kc   = t >> 11;
    int k = kc * 32 + (lane >> 4) * 8 + j;
    int c = ct * 16 + (lane & 15);
    Wf[t] = (_Float16)W[k * OUT_D + c];
}

// Block: 256 thr / 4 waves; wave: 16 rows x 64 cols, K=256 in 8 chunks.
// C/D layout (m89): col = lane&15, row = (lane>>4)*4 + reg.
__global__ __launch_bounds__(256) void k_gemmf16(
        const float* __restrict__ feat, const _Float16* __restrict__ Wf,
        const float* __restrict__ a,
        _Float16* __restrict__ z, float* __restrict__ el, float* __restrict__ er,
        int n)
{
    __shared__ __align__(16) _Float16 WfL[IN_D * OUT_D];   // 32 KB, frag order

    const int tid  = threadIdx.x;
    const int lane = tid & 63;
    const int wv   = tid >> 6;
    const int row0 = blockIdx.x * 64 + wv * 16;
    const int kg   = lane >> 4;

    int gr = row0 + (lane & 15); if (gr > n - 1) gr = n - 1;
    const float* frow = feat + (size_t)gr * IN_D;
    float4 r0[8], r1[8];
    #pragma unroll
    for (int kc = 0; kc < 8; ++kc) {
        const float4* fp = (const float4*)(frow + kc * 32 + kg * 8);
        r0[kc] = fp[0];
        r1[kc] = fp[1];
    }

    #pragma unroll
    for (int i = 0; i < 8; ++i) {
        const char* gsrc = (const char*)Wf + (size_t)(i * 256 + tid) * 16;
        char* ldst = (char*)WfL + (size_t)(i * 256 + wv * 64) * 16;
        gload_lds16(gsrc, ldst);
    }
    __syncthreads();

    f32x4 acc[4];
    #pragma unroll
    for (int ct = 0; ct < 4; ++ct) acc[ct] = (f32x4){0.f, 0.f, 0.f, 0.f};

    #pragma unroll
    for (int kc = 0; kc < 8; ++kc) {
        f16x8 af;
        af[0] = (_Float16)r0[kc].x; af[1] = (_Float16)r0[kc].y;
        af[2] = (_Float16)r0[kc].z; af[3] = (_Float16)r0[kc].w;
        af[4] = (_Float16)r1[kc].x; af[5] = (_Float16)r1[kc].y;
        af[6] = (_Float16)r1[kc].z; af[7] = (_Float16)r1[kc].w;
        #pragma unroll
        for (int ct = 0; ct < 4; ++ct) {
            f16x8 bf = *(const f16x8*)&WfL[((kc * 4 + ct) * 64 + lane) * 8];
            acc[ct] = __builtin_amdgcn_mfma_f32_16x16x32_f16(af, bf, acc[ct], 0, 0, 0);
        }
    }

    const int col = lane & 15;
    float av[4], bv[4];
    #pragma unroll
    for (int ct = 0; ct < 4; ++ct) {
        av[ct] = a[ct * 16 + col];
        bv[ct] = a[OUT_D + ct * 16 + col];
    }
    #pragma unroll
    for (int i = 0; i < 4; ++i) {
        const int r = row0 + (lane >> 4) * 4 + i;
        float vl = 0.f, vr = 0.f;
        #pragma unroll
        for (int ct = 0; ct < 4; ++ct) {
            float zv = acc[ct][i];
            if (r < n) z[(size_t)r * OUT_D + ct * 16 + col] = (_Float16)zv;
            vl = fmaf(zv, av[ct], vl);
            vr = fmaf(zv, bv[ct], vr);
        }
        #pragma unroll
        for (int msk = 8; msk >= 1; msk >>= 1) {
            vl += __shfl_xor(vl, msk, 64);
            vr += __shfl_xor(vr, msk, 64);
        }
        if (col == 0 && r < n) { el[r] = vl; er[r] = vr; }
    }
}

// One wave per destination node; lane = output column. Online softmax with
// flash-style rescale; (ex, s) staged per-chunk in LDS, read back wave-uniform.
__global__ __launch_bounds__(256) void k_agg(
        const _Float16* __restrict__ z, const float* __restrict__ el,
        const float* __restrict__ er, const int* __restrict__ deg_,
        const int* __restrict__ off_, const uint16_t* __restrict__ adj,
        float* __restrict__ out, int n)
{
    __shared__ float exs[WAVES_PB][64];
    __shared__ int   sss[WAVES_PB][64];
    const int lane = threadIdx.x & 63;
    const int wv   = threadIdx.x >> 6;
    const int d = blockIdx.x * WAVES_PB + wv;
    if (d >= n) return;

    const int deg  = deg_[d];
    const int base = off_[d] - deg;        // off[d] = segment END post-scatter
    const float erd = er[d];

    float m = -INFINITY, den = 0.f, acc = 0.f;
    for (int b0 = 0; b0 < deg; b0 += 64) {
        const int i = b0 + lane;
        int s = 0;
        float lgv = -INFINITY;
        if (i < deg) {
            s = adj[base + i];
            float x = el[s] + erd;
            lgv = x > 0.f ? x : 0.01f * x;   // leaky_relu(0.01)
        }
        float cm = lgv;
        #pragma unroll
        for (int msk = 32; msk >= 1; msk >>= 1) cm = fmaxf(cm, __shfl_xor(cm, msk, 64));
        const float newm = fmaxf(m, cm);
        const float ex = (i < deg) ? __expf(lgv - newm) : 0.f;
        exs[wv][lane] = ex;                 // ex==0 pads invalid lanes
        sss[wv][lane] = s;
        float sum = ex;
        #pragma unroll
        for (int msk = 32; msk >= 1; msk >>= 1) sum += __shfl_xor(sum, msk, 64);
        const float scale = __expf(m - newm);   // first iter: exp(-inf)=0
        den = den * scale + sum;
        acc *= scale;
        m = newm;
        asm volatile("s_waitcnt lgkmcnt(0)" ::: "memory");  // wave-local LDS visible

        const int cd  = (deg - b0 < 64) ? deg - b0 : 64;
        const int cd8 = (cd + 7) & ~7;          // padded lanes contribute 0
        #pragma unroll 8
        for (int j = 0; j < cd8; ++j) {
            const float wj = exs[wv][j];        // wave-uniform -> broadcast
            const int   sj = sss[wv][j];
            acc = fmaf(wj, (float)z[(size_t)sj * OUT_D + lane], acc);
        }
    }
    const float h = (deg > 0) ? acc / den : 0.f;
    out[(size_t)d * OUT_D + lane] = h > 0.f ? h : expm1f(h);  // elu
}

extern "C" void kernel_launch(void* const* d_in, const int* in_sizes, int n_in,
                              void* d_out, int out_size, void* d_ws, size_t ws_size,
                              hipStream_t stream) {
    const float* feat = (const float*)d_in[0];
    const float* W    = (const float*)d_in[1];
    const float* a    = (const float*)d_in[2];
    const int*   src  = (const int*)d_in[3];
    const int*   dst  = (const int*)d_in[4];
    const int n = in_sizes[0] / IN_D;
    const int E = in_sizes[3];
    float* out = (float*)d_out;

    // ws: z_h(f16) | el | er | deg | off | counter | Wf(f16) | adj(u16)
    char* ws = (char*)d_ws;
    _Float16* z_h = (_Float16*)ws;  ws += (size_t)n * OUT_D * 2;
    float* el = (float*)ws;         ws += (size_t)n * 4;
    float* er = (float*)ws;         ws += (size_t)n * 4;
    int*  deg = (int*)ws;           ws += (size_t)n * 4;
    int*  off = (int*)ws;           ws += (size_t)n * 4;
    int*  counter = (int*)ws;       ws += 16;
    _Float16* Wf = (_Float16*)ws;   ws += (size_t)IN_D * OUT_D * 2;
    uint16_t* adj = (uint16_t*)ws;

    k_zero<<<(n + 256) / 256, 256, 0, stream>>>(deg, counter, n);
    k_hist<<<(E + 255) / 256, 256, 0, stream>>>(dst, deg, E);
    k_alloc<<<(n + 255) / 256, 256, 0, stream>>>(deg, off, counter, n);
    k_scatter<<<(E + 255) / 256, 256, 0, stream>>>(dst, src, off, adj, E);
    k_wconv<<<IN_D * OUT_D / 256, 256, 0, stream>>>(W, Wf);
    k_gemmf16<<<(n + 63) / 64, 256, 0, stream>>>(feat, Wf, a, z_h, el, er, n);
    k_agg<<<(n + WAVES_PB - 1) / WAVES_PB, 256, 0, stream>>>(z_h, el, er, deg, off, adj, out, n);
}

// Round 6
// 167.226 us; speedup vs baseline: 1.6971x; 1.2787x over previous
//
#include <hip/hip_runtime.h>
#include <math.h>
#include <stdint.h>

// Single-head GAT layer, MI355X (gfx950).
// CSR build with ZERO global atomics (two-level bucket sort):
//   k_count : per-block LDS histogram over coarse buckets (dst>>6)
//   k_bsum  : prefix along blocks per bucket -> blkcnt=prefix, total
//   k_scan1 : exclusive scan of bucket totals (1024-elem LDS scan)
//   k_bin   : re-read edges, LDS cursors -> packed (dst<<16|src) into bucket slot
//   k_fine  : per bucket: 64-bin LDS histogram + wave scan -> deg/off/adj(u16)
// Math:
//   k_wconv   : W f32[256][64] -> f16 B-fragment-ordered Wf (32KB)
//   k_gemmf16 : z = X@W via mfma_f32_16x16x32_f16, fused el/er; z stored f16
//   k_agg     : per-dst wave: online segment softmax + weighted gather of z

constexpr int IN_D   = 256;
constexpr int OUT_D  = 64;
constexpr int WAVES_PB = 4;
constexpr int NBLK   = 256;    // binning blocks
constexpr int NBMAX  = 1024;   // max coarse buckets (n <= 65536)

typedef _Float16 f16x8 __attribute__((ext_vector_type(8)));
typedef float    f32x4 __attribute__((ext_vector_type(4)));

__device__ __forceinline__ void gload_lds16(const void* g, void* l) {
    __builtin_amdgcn_global_load_lds(
        (const __attribute__((address_space(1))) uint32_t*)g,
        (__attribute__((address_space(3))) uint32_t*)l, 16, 0, 0);
}

// ---- build phase ----

__global__ __launch_bounds__(256) void k_count(const int* __restrict__ dst,
                                               int* __restrict__ blkcnt,
                                               int E, int nb, int chunk) {
    __shared__ int cnt[NBMAX];
    const int b = blockIdx.x, tid = threadIdx.x;
    for (int i = tid; i < nb; i += 256) cnt[i] = 0;
    __syncthreads();
    const int lo = b * chunk;
    const int hi = (lo + chunk < E) ? lo + chunk : E;
    for (int e = lo + tid; e < hi; e += 256) atomicAdd(&cnt[dst[e] >> 6], 1);
    __syncthreads();
    for (int i = tid; i < nb; i += 256) blkcnt[(size_t)b * NBMAX + i] = cnt[i];
}

__global__ __launch_bounds__(256) void k_bsum(int* __restrict__ blkcnt,
                                              int* __restrict__ total, int nb) {
    const int j = blockIdx.x * 256 + threadIdx.x;
    if (j >= nb) return;
    int run = 0;
    #pragma unroll 8
    for (int b = 0; b < NBLK; ++b) {
        int v = blkcnt[(size_t)b * NBMAX + j];
        blkcnt[(size_t)b * NBMAX + j] = run;   // prefix of blocks < b
        run += v;
    }
    total[j] = run;
}

__global__ __launch_bounds__(1024) void k_scan1(const int* __restrict__ total,
                                                int* __restrict__ bbase, int nb) {
    __shared__ int sh[1024];
    const int t = threadIdx.x;
    int v = (t < nb) ? total[t] : 0;
    sh[t] = v;
    __syncthreads();
    int acc = v;
    for (int ofs = 1; ofs < 1024; ofs <<= 1) {
        int u = (t >= ofs) ? sh[t - ofs] : 0;
        __syncthreads();
        acc += u;
        sh[t] = acc;
        __syncthreads();
    }
    if (t < nb) bbase[t] = acc - v;            // exclusive
}

__global__ __launch_bounds__(256) void k_bin(const int* __restrict__ dst,
                                             const int* __restrict__ src,
                                             const int* __restrict__ blkcnt,
                                             const int* __restrict__ bbase,
                                             uint32_t* __restrict__ binned,
                                             int E, int nb, int chunk) {
    __shared__ int cur[NBMAX];
    const int b = blockIdx.x, tid = threadIdx.x;
    for (int i = tid; i < nb; i += 256)
        cur[i] = bbase[i] + blkcnt[(size_t)b * NBMAX + i];
    __syncthreads();
    const int lo = b * chunk;
    const int hi = (lo + chunk < E) ? lo + chunk : E;
    for (int e = lo + tid; e < hi; e += 256) {
        const uint32_t d = (uint32_t)dst[e];
        const int pos = atomicAdd(&cur[d >> 6], 1);
        binned[pos] = (d << 16) | (uint32_t)src[e];
    }
}

__global__ __launch_bounds__(256) void k_fine(const uint32_t* __restrict__ binned,
                                              const int* __restrict__ bbase,
                                              const int* __restrict__ total,
                                              uint16_t* __restrict__ adj,
                                              int* __restrict__ deg,
                                              int* __restrict__ off, int n) {
    __shared__ int fcnt[64], foff[64], fcur[64];
    const int j = blockIdx.x, tid = threadIdx.x;
    const int ebase = bbase[j];
    const int ecount = total[j];
    if (tid < 64) { fcnt[tid] = 0; fcur[tid] = 0; }
    __syncthreads();
    for (int i = tid; i < ecount; i += 256)
        atomicAdd(&fcnt[(binned[ebase + i] >> 16) & 63], 1);
    __syncthreads();
    if (tid < 64) {
        const int v = fcnt[tid];
        int incl = v;
        #pragma unroll
        for (int ofs = 1; ofs < 64; ofs <<= 1) {
            int u = __shfl_up(incl, ofs, 64);
            if (tid >= ofs) incl += u;
        }
        foff[tid] = incl - v;
        const int d = j * 64 + tid;
        if (d < n) { deg[d] = v; off[d] = ebase + incl - v; }
    }
    __syncthreads();
    for (int i = tid; i < ecount; i += 256) {
        const uint32_t u = binned[ebase + i];
        const int ld = (u >> 16) & 63;
        const int r = atomicAdd(&fcur[ld], 1);
        adj[ebase + foff[ld] + r] = (uint16_t)(u & 0xFFFFu);
    }
}

// ---- math phase ----

// Wf[t], t = ((kc*4+ct)*64+lane)*8+j  holds W[kc*32+(lane>>4)*8+j][ct*16+(lane&15)]
__global__ void k_wconv(const float* __restrict__ W, _Float16* __restrict__ Wf) {
    int t = blockIdx.x * 256 + threadIdx.x;          // 16384 total
    int j    = t & 7;
    int lane = (t >> 3) & 63;
    int ct   = (t >> 9) & 3;
    int kc   = t >> 11;
    int k = kc * 32 + (lane >> 4) * 8 + j;
    int c = ct * 16 + (lane & 15);
    Wf[t] = (_Float16)W[k * OUT_D + c];
}

// Block: 256 thr / 4 waves; wave: 16 rows x 64 cols, K=256 in 8 chunks.
// C/D layout (m89): col = lane&15, row = (lane>>4)*4 + reg.
__global__ __launch_bounds__(256) void k_gemmf16(
        const float* __restrict__ feat, const _Float16* __restrict__ Wf,
        const float* __restrict__ a,
        _Float16* __restrict__ z, float* __restrict__ el, float* __restrict__ er,
        int n)
{
    __shared__ __align__(16) _Float16 WfL[IN_D * OUT_D];   // 32 KB, frag order

    const int tid  = threadIdx.x;
    const int lane = tid & 63;
    const int wv   = tid >> 6;
    const int row0 = blockIdx.x * 64 + wv * 16;
    const int kg   = lane >> 4;

    int gr = row0 + (lane & 15); if (gr > n - 1) gr = n - 1;
    const float* frow = feat + (size_t)gr * IN_D;
    float4 r0[8], r1[8];
    #pragma unroll
    for (int kc = 0; kc < 8; ++kc) {
        const float4* fp = (const float4*)(frow + kc * 32 + kg * 8);
        r0[kc] = fp[0];
        r1[kc] = fp[1];
    }

    #pragma unroll
    for (int i = 0; i < 8; ++i) {
        const char* gsrc = (const char*)Wf + (size_t)(i * 256 + tid) * 16;
        char* ldst = (char*)WfL + (size_t)(i * 256 + wv * 64) * 16;
        gload_lds16(gsrc, ldst);
    }
    __syncthreads();

    f32x4 acc[4];
    #pragma unroll
    for (int ct = 0; ct < 4; ++ct) acc[ct] = (f32x4){0.f, 0.f, 0.f, 0.f};

    #pragma unroll
    for (int kc = 0; kc < 8; ++kc) {
        f16x8 af;
        af[0] = (_Float16)r0[kc].x; af[1] = (_Float16)r0[kc].y;
        af[2] = (_Float16)r0[kc].z; af[3] = (_Float16)r0[kc].w;
        af[4] = (_Float16)r1[kc].x; af[5] = (_Float16)r1[kc].y;
        af[6] = (_Float16)r1[kc].z; af[7] = (_Float16)r1[kc].w;
        #pragma unroll
        for (int ct = 0; ct < 4; ++ct) {
            f16x8 bf = *(const f16x8*)&WfL[((kc * 4 + ct) * 64 + lane) * 8];
            acc[ct] = __builtin_amdgcn_mfma_f32_16x16x32_f16(af, bf, acc[ct], 0, 0, 0);
        }
    }

    const int col = lane & 15;
    float av[4], bv[4];
    #pragma unroll
    for (int ct = 0; ct < 4; ++ct) {
        av[ct] = a[ct * 16 + col];
        bv[ct] = a[OUT_D + ct * 16 + col];
    }
    #pragma unroll
    for (int i = 0; i < 4; ++i) {
        const int r = row0 + (lane >> 4) * 4 + i;
        float vl = 0.f, vr = 0.f;
        #pragma unroll
        for (int ct = 0; ct < 4; ++ct) {
            float zv = acc[ct][i];
            if (r < n) z[(size_t)r * OUT_D + ct * 16 + col] = (_Float16)zv;
            vl = fmaf(zv, av[ct], vl);
            vr = fmaf(zv, bv[ct], vr);
        }
        #pragma unroll
        for (int msk = 8; msk >= 1; msk >>= 1) {
            vl += __shfl_xor(vl, msk, 64);
            vr += __shfl_xor(vr, msk, 64);
        }
        if (col == 0 && r < n) { el[r] = vl; er[r] = vr; }
    }
}

// One wave per destination node; lane = output column. Online softmax with
// flash-style rescale; (ex, s) staged per-chunk in LDS, read back wave-uniform.
__global__ __launch_bounds__(256) void k_agg(
        const _Float16* __restrict__ z, const float* __restrict__ el,
        const float* __restrict__ er, const int* __restrict__ deg_,
        const int* __restrict__ off_, const uint16_t* __restrict__ adj,
        float* __restrict__ out, int n)
{
    __shared__ float exs[WAVES_PB][64];
    __shared__ int   sss[WAVES_PB][64];
    const int lane = threadIdx.x & 63;
    const int wv   = threadIdx.x >> 6;
    const int d = blockIdx.x * WAVES_PB + wv;
    if (d >= n) return;

    const int deg  = deg_[d];
    const int base = off_[d];              // segment START
    const float erd = er[d];

    float m = -INFINITY, den = 0.f, acc = 0.f;
    for (int b0 = 0; b0 < deg; b0 += 64) {
        const int i = b0 + lane;
        int s = 0;
        float lgv = -INFINITY;
        if (i < deg) {
            s = adj[base + i];
            float x = el[s] + erd;
            lgv = x > 0.f ? x : 0.01f * x;   // leaky_relu(0.01)
        }
        float cm = lgv;
        #pragma unroll
        for (int msk = 32; msk >= 1; msk >>= 1) cm = fmaxf(cm, __shfl_xor(cm, msk, 64));
        const float newm = fmaxf(m, cm);
        const float ex = (i < deg) ? __expf(lgv - newm) : 0.f;
        exs[wv][lane] = ex;                 // ex==0 pads invalid lanes
        sss[wv][lane] = s;
        float sum = ex;
        #pragma unroll
        for (int msk = 32; msk >= 1; msk >>= 1) sum += __shfl_xor(sum, msk, 64);
        const float scale = __expf(m - newm);   // first iter: exp(-inf)=0
        den = den * scale + sum;
        acc *= scale;
        m = newm;
        asm volatile("s_waitcnt lgkmcnt(0)" ::: "memory");

        const int cd  = (deg - b0 < 64) ? deg - b0 : 64;
        const int cd8 = (cd + 7) & ~7;          // padded lanes contribute 0
        #pragma unroll 8
        for (int j = 0; j < cd8; ++j) {
            const float wj = exs[wv][j];        // wave-uniform -> broadcast
            const int   sj = sss[wv][j];
            acc = fmaf(wj, (float)z[(size_t)sj * OUT_D + lane], acc);
        }
    }
    const float h = (deg > 0) ? acc / den : 0.f;
    out[(size_t)d * OUT_D + lane] = h > 0.f ? h : expm1f(h);  // elu
}

extern "C" void kernel_launch(void* const* d_in, const int* in_sizes, int n_in,
                              void* d_out, int out_size, void* d_ws, size_t ws_size,
                              hipStream_t stream) {
    const float* feat = (const float*)d_in[0];
    const float* W    = (const float*)d_in[1];
    const float* a    = (const float*)d_in[2];
    const int*   src  = (const int*)d_in[3];
    const int*   dst  = (const int*)d_in[4];
    const int n = in_sizes[0] / IN_D;
    const int E = in_sizes[3];
    float* out = (float*)d_out;

    const int nb    = (n + 63) >> 6;                 // coarse buckets (<= NBMAX)
    const int chunk = (E + NBLK - 1) / NBLK;

    // ws: z_h | el | er | deg | off | total | bbase | blkcnt | binned | Wf | adj
    char* ws = (char*)d_ws;
    _Float16* z_h = (_Float16*)ws;  ws += (size_t)n * OUT_D * 2;
    float* el = (float*)ws;         ws += (size_t)n * 4;
    float* er = (float*)ws;         ws += (size_t)n * 4;
    int*  deg = (int*)ws;           ws += (size_t)n * 4;
    int*  off = (int*)ws;           ws += (size_t)n * 4;
    int*  total = (int*)ws;         ws += (size_t)NBMAX * 4;
    int*  bbase = (int*)ws;         ws += (size_t)NBMAX * 4;
    int*  blkcnt = (int*)ws;        ws += (size_t)NBLK * NBMAX * 4;
    uint32_t* binned = (uint32_t*)ws; ws += (size_t)E * 4;
    _Float16* Wf = (_Float16*)ws;   ws += (size_t)IN_D * OUT_D * 2;
    uint16_t* adj = (uint16_t*)ws;

    k_count<<<NBLK, 256, 0, stream>>>(dst, blkcnt, E, nb, chunk);
    k_bsum<<<(nb + 255) / 256, 256, 0, stream>>>(blkcnt, total, nb);
    k_scan1<<<1, 1024, 0, stream>>>(total, bbase, nb);
    k_bin<<<NBLK, 256, 0, stream>>>(dst, src, blkcnt, bbase, binned, E, nb, chunk);
    k_fine<<<nb, 256, 0, stream>>>(binned, bbase, total, adj, deg, off, n);

    k_wconv<<<IN_D * OUT_D / 256, 256, 0, stream>>>(W, Wf);
    k_gemmf16<<<(n + 63) / 64, 256, 0, stream>>>(feat, Wf, a, z_h, el, er, n);
    k_agg<<<(n + WAVES_PB - 1) / WAVES_PB, 256, 0, stream>>>(z_h, el, er, deg, off, adj, out, n);
}